// Round 8
// baseline (80.043 us; speedup 1.0000x reference)
//
#include <hip/hip_runtime.h>
#include <cstddef>

#define BB 4
#define NN 256
#define HH 256
#define BN_EPS 1e-5f
#define ETA_EPS 1e-20f

typedef float f4 __attribute__((ext_vector_type(4)));

__device__ __forceinline__ float fast_sigmoid(float x) {
    float ex = __expf(-x);
    return __builtin_amdgcn_rcpf(1.f + ex);
}

// ---------------------------------------------------------------------------
// Kernel 0: transpose W1,W2 -> WT1,WT2 (WT[h][o] = W[o][h]). 32 blocks.
// ---------------------------------------------------------------------------
__global__ __launch_bounds__(256) void transpose_kernel(
    const float* __restrict__ W1, const float* __restrict__ W2,
    float* __restrict__ WT1, float* __restrict__ WT2)
{
    const int which = blockIdx.x >> 4;
    const int tile  = blockIdx.x & 15;
    const int tr = (tile >> 2) << 6, tc = (tile & 3) << 6;
    const float* __restrict__ W  = which ? W2 : W1;
    float* __restrict__ WT       = which ? WT2 : WT1;

    __shared__ float tl[64][65];
    const int c = threadIdx.x & 63, p0 = threadIdx.x >> 6;
#pragma unroll
    for (int p = 0; p < 16; ++p) {
        int r = p * 4 + p0;
        tl[c][r] = W[(tr + r) * HH + tc + c];
    }
    __syncthreads();
#pragma unroll
    for (int p = 0; p < 16; ++p) {
        int cc = p * 4 + p0;
        WT[(tc + cc) * HH + tr + c] = tl[cc][c];
    }
}

// ---------------------------------------------------------------------------
// Kernel 1: projections via WT.  out[r][o] = sum_h x[r][h] * WT[h][o].
// grid = 256 blocks: [0,128) -> WT1/xleft, [128,256) -> WT2/xw2. (proven)
// ---------------------------------------------------------------------------
__global__ __launch_bounds__(256) void proj_kernel(
    const float* __restrict__ nodes, const float* __restrict__ WT1,
    const float* __restrict__ WT2, float* __restrict__ xleft,
    float* __restrict__ xw2)
{
    const int which = blockIdx.x >> 7;
    const int rb    = blockIdx.x & 127;   // 8-row group
    const float* __restrict__ WT = which ? WT2 : WT1;
    float* __restrict__ out      = which ? xw2 : xleft;
    const int t = threadIdx.x;

    __shared__ float xs[8][HH];           // 8 KB
    {
        f4* xs4 = reinterpret_cast<f4*>(xs);
        const f4* nodes4 = reinterpret_cast<const f4*>(nodes) + rb * 512;
#pragma unroll
        for (int m = 0; m < 2; ++m) xs4[m * 256 + t] = nodes4[m * 256 + t];
    }
    __syncthreads();

    const int oq = t & 63;
    const int hg = t >> 6;
    const f4* __restrict__ WT4 = reinterpret_cast<const f4*>(WT);

    f4 acc[8];
#pragma unroll
    for (int r = 0; r < 8; ++r) acc[r] = (f4){0.f, 0.f, 0.f, 0.f};

    for (int hh = 0; hh < 64; ++hh) {
        const int h = hg * 64 + hh;
        f4 wv = WT4[h * 64 + oq];         // coalesced 1 KB per wave
#pragma unroll
        for (int r = 0; r < 8; ++r)
            acc[r] += xs[r][h] * wv;      // LDS broadcast
    }

    __shared__ f4 ps[4][8][64];           // 32 KB
#pragma unroll
    for (int r = 0; r < 8; ++r) ps[hg][r][oq] = acc[r];
    __syncthreads();

#pragma unroll
    for (int m = 0; m < 2; ++m) {
        int idx = m * 256 + t;
        int r = idx >> 6, o = idx & 63;
        f4 v = ps[0][r][o] + ps[1][r][o] + ps[2][r][o] + ps[3][r][o];
        reinterpret_cast<f4*>(out)[(rb * 8 + r) * 64 + o] = v;
    }
}

// ---------------------------------------------------------------------------
// Kernel 2: edge partial sums. 4096 blocks x 256 thr, LB(256,8) caps VGPR
// at 64 -> 8 independent blocks/CU (32 waves/CU); small blocks mean barrier
// tails overlap with other blocks' streaming (the previous 1024-thr versions
// were likely 1 resident block/CU: every __syncthreads drained the CU).
// Block = (bi, j-quarter); wave w streams j in [jq*64+w*16, +16): 16 KB
// fully contiguous. Partials (S0,S1) per (jq,bi,q) go to workspace.
// ---------------------------------------------------------------------------
__global__ __launch_bounds__(256, 8) void edge_kernel(
    const float* __restrict__ edges, const float* __restrict__ xw2,
    f4* __restrict__ psum)
{
    const int blk = blockIdx.x;
    const int bi  = blk >> 2;          // b*N + i
    const int jq  = blk & 3;           // j-quarter
    const int b   = bi >> 8;
    const int t   = threadIdx.x;
    const int q   = t & 63;            // f4 quad over all 256 channels
    const int w   = t >> 6;            // wave 0..3
    const int j0  = jq * 64 + w * 16;

    const f4* __restrict__ e4 =
        reinterpret_cast<const f4*>(edges) + ((size_t)bi * NN + j0) * 64 + q;
    const f4* __restrict__ xw4 =
        reinterpret_cast<const f4*>(xw2) + ((size_t)b * NN + j0) * 64 + q;

    f4 s0 = (f4){0.f, 0.f, 0.f, 0.f};
    f4 s1 = (f4){0.f, 0.f, 0.f, 0.f};

#pragma unroll 2
    for (int jj = 0; jj < 16; ++jj) {
        f4 e  = __builtin_nontemporal_load(e4 + jj * 64);
        f4 xw = xw4[jj * 64];
#pragma unroll
        for (int k = 0; k < 4; ++k) {
            float sg = fast_sigmoid(e[k]);
            s0[k] += sg;
            s1[k] += sg * xw[k];
        }
    }

    __shared__ f4 r0[4][64];           // 4 KB
    __shared__ f4 r1[4][64];
    r0[w][q] = s0;
    r1[w][q] = s1;
    __syncthreads();

    if (t < 64) {
        f4 S0 = r0[0][t] + r0[1][t] + r0[2][t] + r0[3][t];
        f4 S1 = r1[0][t] + r1[1][t] + r1[2][t] + r1[3][t];
        f4* p = psum + (((size_t)jq * 1024 + bi) * 64 + t) * 2;
        p[0] = S0;                     // lane t writes 32 B contiguous
        p[1] = S1;
    }
}

// ---------------------------------------------------------------------------
// Kernel 2b: finish = sum 4 j-quarter partials + xleft -> equ.
// 256 blocks x 256 thr, one thread per (bi, q). ~12 MB traffic.
// Fixed ascending jq order -> deterministic.
// ---------------------------------------------------------------------------
__global__ __launch_bounds__(256) void finish_kernel(
    const f4* __restrict__ psum, const float* __restrict__ xleft,
    float* __restrict__ equ)
{
    const int idx = blockIdx.x * 256 + threadIdx.x;  // bi*64 + q
    f4 S0 = (f4){0.f, 0.f, 0.f, 0.f};
    f4 S1 = (f4){0.f, 0.f, 0.f, 0.f};
#pragma unroll
    for (int jq = 0; jq < 4; ++jq) {
        const f4* p = psum + ((size_t)jq * 65536 + idx) * 2;
        S0 += p[0];
        S1 += p[1];
    }
    f4 xl = reinterpret_cast<const f4*>(xleft)[idx];
    f4 o;
#pragma unroll
    for (int k = 0; k < 4; ++k) o[k] = xl[k] + S1[k] / (S0[k] + ETA_EPS);
    reinterpret_cast<f4*>(equ)[idx] = o;
}

// ---------------------------------------------------------------------------
// Kernel 3: fused BN stats + normalize. 64 blocks x 1024 thr; block owns one
// f4 channel quad. Row quad held in register across both phases.
// ---------------------------------------------------------------------------
__global__ __launch_bounds__(1024) void statsnorm_kernel(
    const float* __restrict__ equ, const float* __restrict__ gamma,
    const float* __restrict__ beta, float* __restrict__ out)
{
    const int cq = blockIdx.x;          // channel quad 0..63
    const int t  = threadIdx.x;         // row 0..1023
    const int lane = t & 63, w = t >> 6;

    f4 v = reinterpret_cast<const f4*>(equ)[t * 64 + cq];
    f4 s = v;
    f4 qs = v * v;

#pragma unroll
    for (int off = 32; off >= 1; off >>= 1) {
#pragma unroll
        for (int k = 0; k < 4; ++k) {
            s[k]  += __shfl_xor(s[k], off);
            qs[k] += __shfl_xor(qs[k], off);
        }
    }

    __shared__ f4 ws_[16][2];
    if (lane == 0) { ws_[w][0] = s; ws_[w][1] = qs; }
    __syncthreads();

    __shared__ f4 sc_s, sh_s;
    if (t == 0) {
        f4 S = (f4){0.f, 0.f, 0.f, 0.f};
        f4 Q = (f4){0.f, 0.f, 0.f, 0.f};
#pragma unroll
        for (int g = 0; g < 16; ++g) { S += ws_[g][0]; Q += ws_[g][1]; }
        const float inv_n = 1.f / (float)(BB * NN);
        f4 gm = reinterpret_cast<const f4*>(gamma)[cq];
        f4 bt = reinterpret_cast<const f4*>(beta)[cq];
        f4 sc, sh;
#pragma unroll
        for (int k = 0; k < 4; ++k) {
            float mean = S[k] * inv_n;
            float var  = Q[k] * inv_n - mean * mean;
            float rstd = rsqrtf(var + BN_EPS);
            sc[k] = rstd * gm[k];
            sh[k] = bt[k] - mean * rstd * gm[k];
        }
        sc_s = sc; sh_s = sh;
    }
    __syncthreads();

    f4 sc = sc_s, sh = sh_s;
    f4 o;
#pragma unroll
    for (int k = 0; k < 4; ++k) o[k] = v[k] * sc[k] + sh[k];
    reinterpret_cast<f4*>(out)[t * 64 + cq] = o;
}

// ---------------------------------------------------------------------------
extern "C" void kernel_launch(void* const* d_in, const int* in_sizes, int n_in,
                              void* d_out, int out_size, void* d_ws, size_t ws_size,
                              hipStream_t stream) {
    (void)in_sizes; (void)n_in; (void)out_size; (void)ws_size;

    const float* nodes = (const float*)d_in[0];
    const float* edges = (const float*)d_in[1];
    const float* W1    = (const float*)d_in[2];
    const float* W2    = (const float*)d_in[3];
    const float* gamma = (const float*)d_in[4];
    const float* beta  = (const float*)d_in[5];
    float* out = (float*)d_out;

    const int nBN_H = BB * NN * HH;  // 262144
    float* ws    = (float*)d_ws;
    float* xleft = ws;
    float* xw2   = ws + nBN_H;
    float* equ   = ws + 2 * nBN_H;
    float* WT1   = ws + 3 * nBN_H;
    float* WT2   = WT1 + HH * HH;
    f4*    psum  = (f4*)(WT2 + HH * HH);   // 4*1024*64*2 f4 = 8 MB

    transpose_kernel<<<32, 256, 0, stream>>>(W1, W2, WT1, WT2);
    proj_kernel<<<256, 256, 0, stream>>>(nodes, WT1, WT2, xleft, xw2);
    edge_kernel<<<BB * NN * 4, 256, 0, stream>>>(edges, xw2, psum);
    finish_kernel<<<256, 256, 0, stream>>>(psum, xleft, equ);
    statsnorm_kernel<<<64, 1024, 0, stream>>>(equ, gamma, beta, out);
}

// Round 9
// 73.983 us; speedup vs baseline: 1.0819x; 1.0819x over previous
//
#include <hip/hip_runtime.h>
#include <cstddef>

#define BB 4
#define NN 256
#define HH 256
#define BN_EPS 1e-5f
#define ETA_EPS 1e-20f

typedef float f4 __attribute__((ext_vector_type(4)));

__device__ __forceinline__ float fast_sigmoid(float x) {
    float ex = __expf(-x);
    return __builtin_amdgcn_rcpf(1.f + ex);
}

// ---------------------------------------------------------------------------
// Kernel 0: transpose W1,W2 -> WT1,WT2 (WT[h][o] = W[o][h]). 32 blocks.
// (R5-proven)
// ---------------------------------------------------------------------------
__global__ __launch_bounds__(256) void transpose_kernel(
    const float* __restrict__ W1, const float* __restrict__ W2,
    float* __restrict__ WT1, float* __restrict__ WT2)
{
    const int which = blockIdx.x >> 4;
    const int tile  = blockIdx.x & 15;
    const int tr = (tile >> 2) << 6, tc = (tile & 3) << 6;
    const float* __restrict__ W  = which ? W2 : W1;
    float* __restrict__ WT       = which ? WT2 : WT1;

    __shared__ float tl[64][65];
    const int c = threadIdx.x & 63, p0 = threadIdx.x >> 6;
#pragma unroll
    for (int p = 0; p < 16; ++p) {
        int r = p * 4 + p0;
        tl[c][r] = W[(tr + r) * HH + tc + c];
    }
    __syncthreads();
#pragma unroll
    for (int p = 0; p < 16; ++p) {
        int cc = p * 4 + p0;
        WT[(tc + cc) * HH + tr + c] = tl[cc][c];
    }
}

// ---------------------------------------------------------------------------
// Kernel 1: projections via WT.  out[r][o] = sum_h x[r][h] * WT[h][o].
// grid = 256 blocks: [0,128) -> WT1/xleft, [128,256) -> WT2/xw2. (R5-proven)
// ---------------------------------------------------------------------------
__global__ __launch_bounds__(256) void proj_kernel(
    const float* __restrict__ nodes, const float* __restrict__ WT1,
    const float* __restrict__ WT2, float* __restrict__ xleft,
    float* __restrict__ xw2)
{
    const int which = blockIdx.x >> 7;
    const int rb    = blockIdx.x & 127;   // 8-row group
    const float* __restrict__ WT = which ? WT2 : WT1;
    float* __restrict__ out      = which ? xw2 : xleft;
    const int t = threadIdx.x;

    __shared__ float xs[8][HH];           // 8 KB
    {
        f4* xs4 = reinterpret_cast<f4*>(xs);
        const f4* nodes4 = reinterpret_cast<const f4*>(nodes) + rb * 512;
#pragma unroll
        for (int m = 0; m < 2; ++m) xs4[m * 256 + t] = nodes4[m * 256 + t];
    }
    __syncthreads();

    const int oq = t & 63;
    const int hg = t >> 6;
    const f4* __restrict__ WT4 = reinterpret_cast<const f4*>(WT);

    f4 acc[8];
#pragma unroll
    for (int r = 0; r < 8; ++r) acc[r] = (f4){0.f, 0.f, 0.f, 0.f};

    for (int hh = 0; hh < 64; ++hh) {
        const int h = hg * 64 + hh;
        f4 wv = WT4[h * 64 + oq];         // coalesced 1 KB per wave
#pragma unroll
        for (int r = 0; r < 8; ++r)
            acc[r] += xs[r][h] * wv;      // LDS broadcast
    }

    __shared__ f4 ps[4][8][64];           // 32 KB
#pragma unroll
    for (int r = 0; r < 8; ++r) ps[hg][r][oq] = acc[r];
    __syncthreads();

#pragma unroll
    for (int m = 0; m < 2; ++m) {
        int idx = m * 256 + t;
        int r = idx >> 6, o = idx & 63;
        f4 v = ps[0][r][o] + ps[1][r][o] + ps[2][r][o] + ps[3][r][o];
        reinterpret_cast<f4*>(out)[(rb * 8 + r) * 64 + o] = v;
    }
}

// ---------------------------------------------------------------------------
// Kernel 2: edge aggregation (R5-proven, best measured total).
// Block = 8 i-rows x 64-channel slice x all j. Grid = 128 i-groups x 4
// slices = 512 blocks x 1024 threads; 64 KB LDS -> 2 blocks/CU.
// xw2 slice staged in LDS once per block (single global stream in the hot
// loop); reduction arrays overlay xw_s after the j-loop.
// ---------------------------------------------------------------------------
__global__ __launch_bounds__(1024) void edge_kernel(
    const float* __restrict__ edges, const float* __restrict__ xw2,
    const float* __restrict__ xleft, float* __restrict__ equ)
{
    const int blk = blockIdx.x;
    const int ig  = blk >> 2;          // i-group of 8 rows: 0..127
    const int hs4 = (blk & 3) * 16;    // first f4 quad of 64-ch slice
    const int bi0 = ig * 8;
    const int b   = bi0 >> 8;
    const int t   = threadIdx.x;

    __shared__ f4 xw_s[NN][16];        // 64 KB; overlaid by reduction later

    const f4* __restrict__ xw4 =
        reinterpret_cast<const f4*>(xw2) + (size_t)b * NN * 64;
#pragma unroll
    for (int m = 0; m < 4; ++m) {
        int idx = m * 1024 + t;
        int j = idx >> 4, q = idx & 15;
        xw_s[j][q] = xw4[j * 64 + hs4 + q];
    }
    __syncthreads();

    const int q  = t & 15;             // channel quad within slice
    const int il = (t >> 4) & 7;       // i within tile
    const int jg = t >> 7;             // 0..7, j stride group

    const f4* __restrict__ erow =
        reinterpret_cast<const f4*>(edges) +
        (size_t)(bi0 + il) * (NN * 64) + hs4 + q;

    float s0[4] = {0.f, 0.f, 0.f, 0.f};
    float s1[4] = {0.f, 0.f, 0.f, 0.f};

#pragma unroll 2
    for (int j = jg; j < NN; j += 8) {
        f4 e  = __builtin_nontemporal_load(erow + j * 64);
        f4 xw = xw_s[j][q];
#pragma unroll
        for (int k = 0; k < 4; ++k) {
            float sg = fast_sigmoid(e[k]);
            s0[k] += sg;
            s1[k] += sg * xw[k];
        }
    }
    __syncthreads();                   // xw_s dead; reuse for reduction

    float* red = reinterpret_cast<float*>(xw_s);
    {
        float* r0 = red + ((jg * 8 + il) * 16 + q) * 4;
        float* r1 = r0 + 4096;
#pragma unroll
        for (int k = 0; k < 4; ++k) { r0[k] = s0[k]; r1[k] = s1[k]; }
    }
    __syncthreads();

    if (t < 512) {
        const int il2 = t >> 6;        // 0..7
        const int ch  = t & 63;        // channel within slice
        float S0 = 0.f, S1 = 0.f;
#pragma unroll
        for (int g = 0; g < 8; ++g) {
            S0 += red[(g * 8 + il2) * 64 + ch];
            S1 += red[(g * 8 + il2) * 64 + ch + 4096];
        }
        const size_t off = (size_t)(bi0 + il2) * HH + hs4 * 4 + ch;
        equ[off] = xleft[off] + S1 / (S0 + ETA_EPS);
    }
}

// ---------------------------------------------------------------------------
// Kernel 3: fused BN stats + normalize (R6-proven). 64 blocks x 1024 thr;
// block owns one f4 channel quad; row quad held in register across phases.
// ---------------------------------------------------------------------------
__global__ __launch_bounds__(1024) void statsnorm_kernel(
    const float* __restrict__ equ, const float* __restrict__ gamma,
    const float* __restrict__ beta, float* __restrict__ out)
{
    const int cq = blockIdx.x;          // channel quad 0..63
    const int t  = threadIdx.x;         // row 0..1023
    const int lane = t & 63, w = t >> 6;

    f4 v = reinterpret_cast<const f4*>(equ)[t * 64 + cq];
    f4 s = v;
    f4 qs = v * v;

#pragma unroll
    for (int off = 32; off >= 1; off >>= 1) {
#pragma unroll
        for (int k = 0; k < 4; ++k) {
            s[k]  += __shfl_xor(s[k], off);
            qs[k] += __shfl_xor(qs[k], off);
        }
    }

    __shared__ f4 ws_[16][2];
    if (lane == 0) { ws_[w][0] = s; ws_[w][1] = qs; }
    __syncthreads();

    __shared__ f4 sc_s, sh_s;
    if (t == 0) {
        f4 S = (f4){0.f, 0.f, 0.f, 0.f};
        f4 Q = (f4){0.f, 0.f, 0.f, 0.f};
#pragma unroll
        for (int g = 0; g < 16; ++g) { S += ws_[g][0]; Q += ws_[g][1]; }
        const float inv_n = 1.f / (float)(BB * NN);
        f4 gm = reinterpret_cast<const f4*>(gamma)[cq];
        f4 bt = reinterpret_cast<const f4*>(beta)[cq];
        f4 sc, sh;
#pragma unroll
        for (int k = 0; k < 4; ++k) {
            float mean = S[k] * inv_n;
            float var  = Q[k] * inv_n - mean * mean;
            float rstd = rsqrtf(var + BN_EPS);
            sc[k] = rstd * gm[k];
            sh[k] = bt[k] - mean * rstd * gm[k];
        }
        sc_s = sc; sh_s = sh;
    }
    __syncthreads();

    f4 sc = sc_s, sh = sh_s;
    f4 o;
#pragma unroll
    for (int k = 0; k < 4; ++k) o[k] = v[k] * sc[k] + sh[k];
    reinterpret_cast<f4*>(out)[t * 64 + cq] = o;
}

// ---------------------------------------------------------------------------
extern "C" void kernel_launch(void* const* d_in, const int* in_sizes, int n_in,
                              void* d_out, int out_size, void* d_ws, size_t ws_size,
                              hipStream_t stream) {
    (void)in_sizes; (void)n_in; (void)out_size; (void)ws_size;

    const float* nodes = (const float*)d_in[0];
    const float* edges = (const float*)d_in[1];
    const float* W1    = (const float*)d_in[2];
    const float* W2    = (const float*)d_in[3];
    const float* gamma = (const float*)d_in[4];
    const float* beta  = (const float*)d_in[5];
    float* out = (float*)d_out;

    const int nBN_H = BB * NN * HH;  // 262144
    float* ws    = (float*)d_ws;
    float* xleft = ws;
    float* xw2   = ws + nBN_H;
    float* equ   = ws + 2 * nBN_H;
    float* WT1   = ws + 3 * nBN_H;
    float* WT2   = WT1 + HH * HH;

    transpose_kernel<<<32, 256, 0, stream>>>(W1, W2, WT1, WT2);
    proj_kernel<<<256, 256, 0, stream>>>(nodes, WT1, WT2, xleft, xw2);
    edge_kernel<<<512, 1024, 0, stream>>>(edges, xw2, xleft, equ);
    statsnorm_kernel<<<64, 1024, 0, stream>>>(equ, gamma, beta, out);
}

// Round 10
// 70.096 us; speedup vs baseline: 1.1419x; 1.0554x over previous
//
#include <hip/hip_runtime.h>
#include <cstddef>

#define BB 4
#define NN 256
#define HH 256
#define BN_EPS 1e-5f
#define ETA_EPS 1e-20f

typedef float f4 __attribute__((ext_vector_type(4)));

__device__ __forceinline__ float fast_sigmoid(float x) {
    float ex = __expf(-x);
    return __builtin_amdgcn_rcpf(1.f + ex);
}

// ---------------------------------------------------------------------------
// Kernel 0: transpose W1,W2 -> WT1,WT2 (WT[h][o] = W[o][h]). 32 blocks.
// (R5-proven)
// ---------------------------------------------------------------------------
__global__ __launch_bounds__(256) void transpose_kernel(
    const float* __restrict__ W1, const float* __restrict__ W2,
    float* __restrict__ WT1, float* __restrict__ WT2)
{
    const int which = blockIdx.x >> 4;
    const int tile  = blockIdx.x & 15;
    const int tr = (tile >> 2) << 6, tc = (tile & 3) << 6;
    const float* __restrict__ W  = which ? W2 : W1;
    float* __restrict__ WT       = which ? WT2 : WT1;

    __shared__ float tl[64][65];
    const int c = threadIdx.x & 63, p0 = threadIdx.x >> 6;
#pragma unroll
    for (int p = 0; p < 16; ++p) {
        int r = p * 4 + p0;
        tl[c][r] = W[(tr + r) * HH + tc + c];
    }
    __syncthreads();
#pragma unroll
    for (int p = 0; p < 16; ++p) {
        int cc = p * 4 + p0;
        WT[(tc + cc) * HH + tr + c] = tl[cc][c];
    }
}

// ---------------------------------------------------------------------------
// Kernel 1: projections via WT.  out[r][o] = sum_h x[r][h] * WT[h][o].
// grid = 256 blocks: [0,128) -> WT1/xleft, [128,256) -> WT2/xw2. (R5-proven)
// ---------------------------------------------------------------------------
__global__ __launch_bounds__(256) void proj_kernel(
    const float* __restrict__ nodes, const float* __restrict__ WT1,
    const float* __restrict__ WT2, float* __restrict__ xleft,
    float* __restrict__ xw2)
{
    const int which = blockIdx.x >> 7;
    const int rb    = blockIdx.x & 127;   // 8-row group
    const float* __restrict__ WT = which ? WT2 : WT1;
    float* __restrict__ out      = which ? xw2 : xleft;
    const int t = threadIdx.x;

    __shared__ float xs[8][HH];           // 8 KB
    {
        f4* xs4 = reinterpret_cast<f4*>(xs);
        const f4* nodes4 = reinterpret_cast<const f4*>(nodes) + rb * 512;
#pragma unroll
        for (int m = 0; m < 2; ++m) xs4[m * 256 + t] = nodes4[m * 256 + t];
    }
    __syncthreads();

    const int oq = t & 63;
    const int hg = t >> 6;
    const f4* __restrict__ WT4 = reinterpret_cast<const f4*>(WT);

    f4 acc[8];
#pragma unroll
    for (int r = 0; r < 8; ++r) acc[r] = (f4){0.f, 0.f, 0.f, 0.f};

    for (int hh = 0; hh < 64; ++hh) {
        const int h = hg * 64 + hh;
        f4 wv = WT4[h * 64 + oq];         // coalesced 1 KB per wave
#pragma unroll
        for (int r = 0; r < 8; ++r)
            acc[r] += xs[r][h] * wv;      // LDS broadcast
    }

    __shared__ f4 ps[4][8][64];           // 32 KB
#pragma unroll
    for (int r = 0; r < 8; ++r) ps[hg][r][oq] = acc[r];
    __syncthreads();

#pragma unroll
    for (int m = 0; m < 2; ++m) {
        int idx = m * 256 + t;
        int r = idx >> 6, o = idx & 63;
        f4 v = ps[0][r][o] + ps[1][r][o] + ps[2][r][o] + ps[3][r][o];
        reinterpret_cast<f4*>(out)[(rb * 8 + r) * 64 + o] = v;
    }
}

// ---------------------------------------------------------------------------
// Kernel 2: edge aggregation — R5 structure EXACTLY, with ONE change:
// the edges load is a plain load (no __builtin_nontemporal_load). The nt
// hint was in every variant R2-R9; suspected read-BW penalty on gfx950.
// ---------------------------------------------------------------------------
__global__ __launch_bounds__(1024) void edge_kernel(
    const float* __restrict__ edges, const float* __restrict__ xw2,
    const float* __restrict__ xleft, float* __restrict__ equ)
{
    const int blk = blockIdx.x;
    const int ig  = blk >> 2;          // i-group of 8 rows: 0..127
    const int hs4 = (blk & 3) * 16;    // first f4 quad of 64-ch slice
    const int bi0 = ig * 8;
    const int b   = bi0 >> 8;
    const int t   = threadIdx.x;

    __shared__ f4 xw_s[NN][16];        // 64 KB; overlaid by reduction later

    const f4* __restrict__ xw4 =
        reinterpret_cast<const f4*>(xw2) + (size_t)b * NN * 64;
#pragma unroll
    for (int m = 0; m < 4; ++m) {
        int idx = m * 1024 + t;
        int j = idx >> 4, q = idx & 15;
        xw_s[j][q] = xw4[j * 64 + hs4 + q];
    }
    __syncthreads();

    const int q  = t & 15;             // channel quad within slice
    const int il = (t >> 4) & 7;       // i within tile
    const int jg = t >> 7;             // 0..7, j stride group

    const f4* __restrict__ erow =
        reinterpret_cast<const f4*>(edges) +
        (size_t)(bi0 + il) * (NN * 64) + hs4 + q;

    float s0[4] = {0.f, 0.f, 0.f, 0.f};
    float s1[4] = {0.f, 0.f, 0.f, 0.f};

#pragma unroll 2
    for (int j = jg; j < NN; j += 8) {
        f4 e  = erow[j * 64];          // plain load (nt removed)
        f4 xw = xw_s[j][q];
#pragma unroll
        for (int k = 0; k < 4; ++k) {
            float sg = fast_sigmoid(e[k]);
            s0[k] += sg;
            s1[k] += sg * xw[k];
        }
    }
    __syncthreads();                   // xw_s dead; reuse for reduction

    float* red = reinterpret_cast<float*>(xw_s);
    {
        float* r0 = red + ((jg * 8 + il) * 16 + q) * 4;
        float* r1 = r0 + 4096;
#pragma unroll
        for (int k = 0; k < 4; ++k) { r0[k] = s0[k]; r1[k] = s1[k]; }
    }
    __syncthreads();

    if (t < 512) {
        const int il2 = t >> 6;        // 0..7
        const int ch  = t & 63;        // channel within slice
        float S0 = 0.f, S1 = 0.f;
#pragma unroll
        for (int g = 0; g < 8; ++g) {
            S0 += red[(g * 8 + il2) * 64 + ch];
            S1 += red[(g * 8 + il2) * 64 + ch + 4096];
        }
        const size_t off = (size_t)(bi0 + il2) * HH + hs4 * 4 + ch;
        equ[off] = xleft[off] + S1 / (S0 + ETA_EPS);
    }
}

// ---------------------------------------------------------------------------
// Kernel 3: BN batch stats. 16 blocks x 1024 threads (R5-proven).
// ---------------------------------------------------------------------------
__global__ __launch_bounds__(1024) void stats_kernel(
    const float* __restrict__ equ, const float* __restrict__ gamma,
    const float* __restrict__ beta, float* __restrict__ scale,
    float* __restrict__ shift)
{
    const int t     = threadIdx.x;
    const int ql    = t & 3;
    const int rg    = t >> 2;
    const int qbase = blockIdx.x * 4;

    const f4* __restrict__ equ4 = reinterpret_cast<const f4*>(equ);

    float s[4] = {0.f, 0.f, 0.f, 0.f};
    float qq[4] = {0.f, 0.f, 0.f, 0.f};
    for (int r = rg; r < BB * NN; r += 256) {
        f4 v = equ4[r * 64 + qbase + ql];
#pragma unroll
        for (int k = 0; k < 4; ++k) { s[k] += v[k]; qq[k] += v[k] * v[k]; }
    }

    __shared__ float sp[256][17];
    __shared__ float qp[256][17];
    __shared__ float sp2[16][17];
    __shared__ float qp2[16][17];
#pragma unroll
    for (int k = 0; k < 4; ++k) { sp[rg][ql * 4 + k] = s[k]; qp[rg][ql * 4 + k] = qq[k]; }
    __syncthreads();

    if (t < 256) {
        const int ch = t & 15, seg = t >> 4;
        float S = 0.f, Q = 0.f;
#pragma unroll
        for (int g = 0; g < 16; ++g) { S += sp[seg * 16 + g][ch]; Q += qp[seg * 16 + g][ch]; }
        sp2[seg][ch] = S; qp2[seg][ch] = Q;
    }
    __syncthreads();

    if (t < 16) {
        float S = 0.f, Q = 0.f;
#pragma unroll
        for (int g = 0; g < 16; ++g) { S += sp2[g][t]; Q += qp2[g][t]; }
        const float inv_n = 1.f / (float)(BB * NN);
        float mean = S * inv_n;
        float var  = Q * inv_n - mean * mean;
        float rstd = rsqrtf(var + BN_EPS);
        int cc = blockIdx.x * 16 + t;
        float g  = gamma[cc];
        float bt = beta[cc];
        scale[cc] = rstd * g;
        shift[cc] = bt - mean * rstd * g;
    }
}

// ---------------------------------------------------------------------------
// Kernel 4: apply normalization. float4 elementwise. (R5-proven)
// ---------------------------------------------------------------------------
__global__ __launch_bounds__(256) void norm_kernel(
    const float* __restrict__ equ, const float* __restrict__ scale,
    const float* __restrict__ shift, float* __restrict__ out)
{
    const int idx = blockIdx.x * 256 + threadIdx.x;
    f4 e  = reinterpret_cast<const f4*>(equ)[idx];
    const int c4 = idx & 63;
    f4 sc = reinterpret_cast<const f4*>(scale)[c4];
    f4 sh = reinterpret_cast<const f4*>(shift)[c4];
    f4 o;
#pragma unroll
    for (int k = 0; k < 4; ++k) o[k] = e[k] * sc[k] + sh[k];
    reinterpret_cast<f4*>(out)[idx] = o;
}

// ---------------------------------------------------------------------------
extern "C" void kernel_launch(void* const* d_in, const int* in_sizes, int n_in,
                              void* d_out, int out_size, void* d_ws, size_t ws_size,
                              hipStream_t stream) {
    (void)in_sizes; (void)n_in; (void)out_size; (void)ws_size;

    const float* nodes = (const float*)d_in[0];
    const float* edges = (const float*)d_in[1];
    const float* W1    = (const float*)d_in[2];
    const float* W2    = (const float*)d_in[3];
    const float* gamma = (const float*)d_in[4];
    const float* beta  = (const float*)d_in[5];
    float* out = (float*)d_out;

    const int nBN_H = BB * NN * HH;  // 262144
    float* ws    = (float*)d_ws;
    float* xleft = ws;
    float* xw2   = ws + nBN_H;
    float* equ   = ws + 2 * nBN_H;
    float* scale = ws + 3 * nBN_H;
    float* shift = ws + 3 * nBN_H + 256;
    float* WT1   = ws + 3 * nBN_H + 512;
    float* WT2   = WT1 + HH * HH;

    transpose_kernel<<<32, 256, 0, stream>>>(W1, W2, WT1, WT2);
    proj_kernel<<<256, 256, 0, stream>>>(nodes, WT1, WT2, xleft, xw2);
    edge_kernel<<<512, 1024, 0, stream>>>(edges, xw2, xleft, equ);
    stats_kernel<<<16, 1024, 0, stream>>>(equ, gamma, beta, scale, shift);
    norm_kernel<<<256, 256, 0, stream>>>(equ, scale, shift, out);
}

// Round 11
// 65.667 us; speedup vs baseline: 1.2189x; 1.0675x over previous
//
#include <hip/hip_runtime.h>
#include <cstddef>

#define BB 4
#define NN 256
#define HH 256
#define BN_EPS 1e-5f
#define ETA_EPS 1e-20f

typedef float f4 __attribute__((ext_vector_type(4)));

__device__ __forceinline__ float fast_sigmoid(float x) {
    float ex = __expf(-x);
    return __builtin_amdgcn_rcpf(1.f + ex);
}

// ---------------------------------------------------------------------------
// Kernel 0: transpose W1,W2 -> WT1,WT2; block 32 zeros the stats accumulators
// (must happen every call: edge accumulates into them atomically).
// ---------------------------------------------------------------------------
__global__ __launch_bounds__(256) void transpose_kernel(
    const float* __restrict__ W1, const float* __restrict__ W2,
    float* __restrict__ WT1, float* __restrict__ WT2,
    float* __restrict__ Ssum, float* __restrict__ Qsum)
{
    if (blockIdx.x == 32) {
        Ssum[threadIdx.x] = 0.f;
        Qsum[threadIdx.x] = 0.f;
        return;
    }
    const int which = blockIdx.x >> 4;
    const int tile  = blockIdx.x & 15;
    const int tr = (tile >> 2) << 6, tc = (tile & 3) << 6;
    const float* __restrict__ W  = which ? W2 : W1;
    float* __restrict__ WT       = which ? WT2 : WT1;

    __shared__ float tl[64][65];
    const int c = threadIdx.x & 63, p0 = threadIdx.x >> 6;
#pragma unroll
    for (int p = 0; p < 16; ++p) {
        int r = p * 4 + p0;
        tl[c][r] = W[(tr + r) * HH + tc + c];
    }
    __syncthreads();
#pragma unroll
    for (int p = 0; p < 16; ++p) {
        int cc = p * 4 + p0;
        WT[(tc + cc) * HH + tr + c] = tl[cc][c];
    }
}

// ---------------------------------------------------------------------------
// Kernel 1: projections via WT.  out[r][o] = sum_h x[r][h] * WT[h][o].
// grid = 256 blocks: [0,128) -> WT1/xleft, [128,256) -> WT2/xw2. (R5-proven)
// ---------------------------------------------------------------------------
__global__ __launch_bounds__(256) void proj_kernel(
    const float* __restrict__ nodes, const float* __restrict__ WT1,
    const float* __restrict__ WT2, float* __restrict__ xleft,
    float* __restrict__ xw2)
{
    const int which = blockIdx.x >> 7;
    const int rb    = blockIdx.x & 127;   // 8-row group
    const float* __restrict__ WT = which ? WT2 : WT1;
    float* __restrict__ out      = which ? xw2 : xleft;
    const int t = threadIdx.x;

    __shared__ float xs[8][HH];           // 8 KB
    {
        f4* xs4 = reinterpret_cast<f4*>(xs);
        const f4* nodes4 = reinterpret_cast<const f4*>(nodes) + rb * 512;
#pragma unroll
        for (int m = 0; m < 2; ++m) xs4[m * 256 + t] = nodes4[m * 256 + t];
    }
    __syncthreads();

    const int oq = t & 63;
    const int hg = t >> 6;
    const f4* __restrict__ WT4 = reinterpret_cast<const f4*>(WT);

    f4 acc[8];
#pragma unroll
    for (int r = 0; r < 8; ++r) acc[r] = (f4){0.f, 0.f, 0.f, 0.f};

    for (int hh = 0; hh < 64; ++hh) {
        const int h = hg * 64 + hh;
        f4 wv = WT4[h * 64 + oq];         // coalesced 1 KB per wave
#pragma unroll
        for (int r = 0; r < 8; ++r)
            acc[r] += xs[r][h] * wv;      // LDS broadcast
    }

    __shared__ f4 ps[4][8][64];           // 32 KB
#pragma unroll
    for (int r = 0; r < 8; ++r) ps[hg][r][oq] = acc[r];
    __syncthreads();

#pragma unroll
    for (int m = 0; m < 2; ++m) {
        int idx = m * 256 + t;
        int r = idx >> 6, o = idx & 63;
        f4 v = ps[0][r][o] + ps[1][r][o] + ps[2][r][o] + ps[3][r][o];
        reinterpret_cast<f4*>(out)[(rb * 8 + r) * 64 + o] = v;
    }
}

// ---------------------------------------------------------------------------
// Kernel 2: edge aggregation (R10 best: R5 structure, plain loads) + fused
// per-channel BN stats partials. After computing equ values, each block
// LDS-reduces its 8 rows per channel and atomicAdds (S, S^2) into the 256-
// channel accumulators. Replaces the standalone stats kernel + one gap.
// ---------------------------------------------------------------------------
__global__ __launch_bounds__(1024) void edge_kernel(
    const float* __restrict__ edges, const float* __restrict__ xw2,
    const float* __restrict__ xleft, float* __restrict__ equ,
    float* __restrict__ Ssum, float* __restrict__ Qsum)
{
    const int blk = blockIdx.x;
    const int ig  = blk >> 2;          // i-group of 8 rows: 0..127
    const int hs4 = (blk & 3) * 16;    // first f4 quad of 64-ch slice
    const int bi0 = ig * 8;
    const int b   = bi0 >> 8;
    const int t   = threadIdx.x;

    __shared__ f4 xw_s[NN][16];        // 64 KB; overlaid by reduction later

    const f4* __restrict__ xw4 =
        reinterpret_cast<const f4*>(xw2) + (size_t)b * NN * 64;
#pragma unroll
    for (int m = 0; m < 4; ++m) {
        int idx = m * 1024 + t;
        int j = idx >> 4, q = idx & 15;
        xw_s[j][q] = xw4[j * 64 + hs4 + q];
    }
    __syncthreads();

    const int q  = t & 15;             // channel quad within slice
    const int il = (t >> 4) & 7;       // i within tile
    const int jg = t >> 7;             // 0..7, j stride group

    const f4* __restrict__ erow =
        reinterpret_cast<const f4*>(edges) +
        (size_t)(bi0 + il) * (NN * 64) + hs4 + q;

    float s0[4] = {0.f, 0.f, 0.f, 0.f};
    float s1[4] = {0.f, 0.f, 0.f, 0.f};

#pragma unroll 2
    for (int j = jg; j < NN; j += 8) {
        f4 e  = erow[j * 64];          // plain load
        f4 xw = xw_s[j][q];
#pragma unroll
        for (int k = 0; k < 4; ++k) {
            float sg = fast_sigmoid(e[k]);
            s0[k] += sg;
            s1[k] += sg * xw[k];
        }
    }
    __syncthreads();                   // xw_s dead; reuse for reduction

    float* red = reinterpret_cast<float*>(xw_s);
    {
        float* r0 = red + ((jg * 8 + il) * 16 + q) * 4;
        float* r1 = r0 + 4096;
#pragma unroll
        for (int k = 0; k < 4; ++k) { r0[k] = s0[k]; r1[k] = s1[k]; }
    }
    __syncthreads();

    // stat partials live past 8192 floats (red uses [0, 8192))
    float* st = red + 8192;            // [8 rows][64 ch][2]

    if (t < 512) {
        const int il2 = t >> 6;        // 0..7 (== wave id)
        const int ch  = t & 63;        // channel within slice
        float S0 = 0.f, S1 = 0.f;
#pragma unroll
        for (int g = 0; g < 8; ++g) {
            S0 += red[(g * 8 + il2) * 64 + ch];
            S1 += red[(g * 8 + il2) * 64 + ch + 4096];
        }
        const size_t off = (size_t)(bi0 + il2) * HH + hs4 * 4 + ch;
        float ov = xleft[off] + S1 / (S0 + ETA_EPS);
        equ[off] = ov;
        st[(il2 * 64 + ch) * 2]     = ov;
        st[(il2 * 64 + ch) * 2 + 1] = ov * ov;
    }
    __syncthreads();

    if (t < 64) {
        float S = 0.f, Q = 0.f;
#pragma unroll
        for (int g = 0; g < 8; ++g) {
            S += st[(g * 64 + t) * 2];
            Q += st[(g * 64 + t) * 2 + 1];
        }
        atomicAdd(&Ssum[hs4 * 4 + t], S);
        atomicAdd(&Qsum[hs4 * 4 + t], Q);
    }
}

// ---------------------------------------------------------------------------
// Kernel 3: normalize with inline scale/shift from the atomic accumulators.
// 256 blocks x 256 thr; Ssum/Qsum/gamma/beta reads are coalesced f4, L2-hot.
// ---------------------------------------------------------------------------
__global__ __launch_bounds__(256) void norm_kernel(
    const float* __restrict__ equ, const float* __restrict__ Ssum,
    const float* __restrict__ Qsum, const float* __restrict__ gamma,
    const float* __restrict__ beta, float* __restrict__ out)
{
    const int idx = blockIdx.x * 256 + threadIdx.x;   // f4 index
    const int c4  = idx & 63;
    f4 e = reinterpret_cast<const f4*>(equ)[idx];
    f4 S = reinterpret_cast<const f4*>(Ssum)[c4];
    f4 Q = reinterpret_cast<const f4*>(Qsum)[c4];
    f4 g = reinterpret_cast<const f4*>(gamma)[c4];
    f4 b = reinterpret_cast<const f4*>(beta)[c4];

    const float inv_n = 1.f / (float)(BB * NN);
    f4 o;
#pragma unroll
    for (int k = 0; k < 4; ++k) {
        float mean = S[k] * inv_n;
        float var  = Q[k] * inv_n - mean * mean;
        float rstd = rsqrtf(var + BN_EPS);
        o[k] = (e[k] - mean) * rstd * g[k] + b[k];
    }
    reinterpret_cast<f4*>(out)[idx] = o;
}

// ---------------------------------------------------------------------------
extern "C" void kernel_launch(void* const* d_in, const int* in_sizes, int n_in,
                              void* d_out, int out_size, void* d_ws, size_t ws_size,
                              hipStream_t stream) {
    (void)in_sizes; (void)n_in; (void)out_size; (void)ws_size;

    const float* nodes = (const float*)d_in[0];
    const float* edges = (const float*)d_in[1];
    const float* W1    = (const float*)d_in[2];
    const float* W2    = (const float*)d_in[3];
    const float* gamma = (const float*)d_in[4];
    const float* beta  = (const float*)d_in[5];
    float* out = (float*)d_out;

    const int nBN_H = BB * NN * HH;  // 262144
    float* ws    = (float*)d_ws;
    float* xleft = ws;
    float* xw2   = ws + nBN_H;
    float* equ   = ws + 2 * nBN_H;
    float* WT1   = ws + 3 * nBN_H;
    float* WT2   = WT1 + HH * HH;
    float* Ssum  = WT2 + HH * HH;
    float* Qsum  = Ssum + HH;

    transpose_kernel<<<33, 256, 0, stream>>>(W1, W2, WT1, WT2, Ssum, Qsum);
    proj_kernel<<<256, 256, 0, stream>>>(nodes, WT1, WT2, xleft, xw2);
    edge_kernel<<<512, 1024, 0, stream>>>(edges, xw2, xleft, equ, Ssum, Qsum);
    norm_kernel<<<256, 256, 0, stream>>>(equ, Ssum, Qsum, gamma, beta, out);
}

// Round 13
// 63.135 us; speedup vs baseline: 1.2678x; 1.0401x over previous
//
#include <hip/hip_runtime.h>
#include <cstddef>

#define BB 4
#define NN 256
#define HH 256
#define BN_EPS 1e-5f
#define ETA_EPS 1e-20f

typedef float f4 __attribute__((ext_vector_type(4)));

__device__ __forceinline__ float fast_sigmoid(float x) {
    float ex = __expf(-x);
    return __builtin_amdgcn_rcpf(1.f + ex);
}

// ---------------------------------------------------------------------------
// Kernel 0: transpose W1,W2 -> WT1,WT2; block 32 zeros the stats accumulators
// (must happen every call: edge accumulates into them atomically).
// ---------------------------------------------------------------------------
__global__ __launch_bounds__(256) void transpose_kernel(
    const float* __restrict__ W1, const float* __restrict__ W2,
    float* __restrict__ WT1, float* __restrict__ WT2,
    float* __restrict__ Ssum, float* __restrict__ Qsum)
{
    if (blockIdx.x == 32) {
        Ssum[threadIdx.x] = 0.f;
        Qsum[threadIdx.x] = 0.f;
        return;
    }
    const int which = blockIdx.x >> 4;
    const int tile  = blockIdx.x & 15;
    const int tr = (tile >> 2) << 6, tc = (tile & 3) << 6;
    const float* __restrict__ W  = which ? W2 : W1;
    float* __restrict__ WT       = which ? WT2 : WT1;

    __shared__ float tl[64][65];
    const int c = threadIdx.x & 63, p0 = threadIdx.x >> 6;
#pragma unroll
    for (int p = 0; p < 16; ++p) {
        int r = p * 4 + p0;
        tl[c][r] = W[(tr + r) * HH + tc + c];
    }
    __syncthreads();
#pragma unroll
    for (int p = 0; p < 16; ++p) {
        int cc = p * 4 + p0;
        WT[(tc + cc) * HH + tr + c] = tl[cc][c];
    }
}

// ---------------------------------------------------------------------------
// Kernel 1: projections via WT.  out[r][o] = sum_h x[r][h] * WT[h][o].
// 512 blocks x 256 thr: blk = wg*4 + which*2 + oh. Block = 8 rows x 128
// outputs of one weight -> 2 blocks/CU (vs R11's 1), same 64 MB logical W
// traffic (each block reads only its output-half's W rows).
// ---------------------------------------------------------------------------
__global__ __launch_bounds__(256) void proj_kernel(
    const float* __restrict__ nodes, const float* __restrict__ WT1,
    const float* __restrict__ WT2, float* __restrict__ xleft,
    float* __restrict__ xw2)
{
    const int wg    = blockIdx.x >> 2;       // 8-row group, 0..127
    const int which = (blockIdx.x >> 1) & 1; // 0 -> W1/xleft, 1 -> W2/xw2
    const int oh    = blockIdx.x & 1;        // output half (32 f4 quads)
    const float* __restrict__ WT = which ? WT2 : WT1;
    float* __restrict__ dst      = which ? xw2 : xleft;
    const int t = threadIdx.x;

    __shared__ float xs[8][HH];              // 8 KB
    {
        f4* xs4 = reinterpret_cast<f4*>(xs);
        const f4* nodes4 = reinterpret_cast<const f4*>(nodes) + wg * 512;
        xs4[t]       = nodes4[t];
        xs4[t + 256] = nodes4[t + 256];
    }
    __syncthreads();

    const int oq = t & 31;                   // f4 quad within this half
    const int hg = t >> 5;                   // h-group 0..7 (32 h each)
    const f4* __restrict__ WT4 = reinterpret_cast<const f4*>(WT);

    f4 acc[8];
#pragma unroll
    for (int r = 0; r < 8; ++r) acc[r] = (f4){0.f, 0.f, 0.f, 0.f};

    for (int hh = 0; hh < 32; ++hh) {
        const int h = hg * 32 + hh;
        f4 wv = WT4[h * 64 + oh * 32 + oq];  // 512 B contiguous per hg-half
#pragma unroll
        for (int r = 0; r < 8; ++r)
            acc[r] += xs[r][h] * wv;         // LDS broadcast
    }

    __shared__ f4 ps[8][8][32];              // 32 KB  [hg][r][oq]
#pragma unroll
    for (int r = 0; r < 8; ++r) ps[hg][r][oq] = acc[r];
    __syncthreads();

    {
        const int r = t >> 5, o = t & 31;    // 256 threads = 8 r x 32 oq
        f4 v = (f4){0.f, 0.f, 0.f, 0.f};
#pragma unroll
        for (int g = 0; g < 8; ++g) v += ps[g][r][o];
        reinterpret_cast<f4*>(dst)[(wg * 8 + r) * 64 + oh * 32 + o] = v;
    }
}

// ---------------------------------------------------------------------------
// Kernel 2: edge aggregation (R11-proven: R5 structure, plain loads) + fused
// per-channel BN stats partials via atomicAdd.
// ---------------------------------------------------------------------------
__global__ __launch_bounds__(1024) void edge_kernel(
    const float* __restrict__ edges, const float* __restrict__ xw2,
    const float* __restrict__ xleft, float* __restrict__ equ,
    float* __restrict__ Ssum, float* __restrict__ Qsum)
{
    const int blk = blockIdx.x;
    const int ig  = blk >> 2;          // i-group of 8 rows: 0..127
    const int hs4 = (blk & 3) * 16;    // first f4 quad of 64-ch slice
    const int bi0 = ig * 8;
    const int b   = bi0 >> 8;
    const int t   = threadIdx.x;

    __shared__ f4 xw_s[NN][16];        // 64 KB; overlaid by reduction later

    const f4* __restrict__ xw4 =
        reinterpret_cast<const f4*>(xw2) + (size_t)b * NN * 64;
#pragma unroll
    for (int m = 0; m < 4; ++m) {
        int idx = m * 1024 + t;
        int j = idx >> 4, q = idx & 15;
        xw_s[j][q] = xw4[j * 64 + hs4 + q];
    }
    __syncthreads();

    const int q  = t & 15;             // channel quad within slice
    const int il = (t >> 4) & 7;       // i within tile
    const int jg = t >> 7;             // 0..7, j stride group

    const f4* __restrict__ erow =
        reinterpret_cast<const f4*>(edges) +
        (size_t)(bi0 + il) * (NN * 64) + hs4 + q;

    float s0[4] = {0.f, 0.f, 0.f, 0.f};
    float s1[4] = {0.f, 0.f, 0.f, 0.f};

#pragma unroll 2
    for (int j = jg; j < NN; j += 8) {
        f4 e  = erow[j * 64];          // plain load
        f4 xw = xw_s[j][q];
#pragma unroll
        for (int k = 0; k < 4; ++k) {
            float sg = fast_sigmoid(e[k]);
            s0[k] += sg;
            s1[k] += sg * xw[k];
        }
    }
    __syncthreads();                   // xw_s dead; reuse for reduction

    float* red = reinterpret_cast<float*>(xw_s);
    {
        float* r0 = red + ((jg * 8 + il) * 16 + q) * 4;
        float* r1 = r0 + 4096;
#pragma unroll
        for (int k = 0; k < 4; ++k) { r0[k] = s0[k]; r1[k] = s1[k]; }
    }
    __syncthreads();

    // stat partials live past 8192 floats (red uses [0, 8192))
    float* st = red + 8192;            // [8 rows][64 ch][2]

    if (t < 512) {
        const int il2 = t >> 6;        // 0..7
        const int ch  = t & 63;        // channel within slice
        float S0 = 0.f, S1 = 0.f;
#pragma unroll
        for (int g = 0; g < 8; ++g) {
            S0 += red[(g * 8 + il2) * 64 + ch];
            S1 += red[(g * 8 + il2) * 64 + ch + 4096];
        }
        const size_t off = (size_t)(bi0 + il2) * HH + hs4 * 4 + ch;
        float ov = xleft[off] + S1 / (S0 + ETA_EPS);
        equ[off] = ov;
        st[(il2 * 64 + ch) * 2]     = ov;
        st[(il2 * 64 + ch) * 2 + 1] = ov * ov;
    }
    __syncthreads();

    if (t < 64) {
        float S = 0.f, Q = 0.f;
#pragma unroll
        for (int g = 0; g < 8; ++g) {
            S += st[(g * 64 + t) * 2];
            Q += st[(g * 64 + t) * 2 + 1];
        }
        atomicAdd(&Ssum[hs4 * 4 + t], S);
        atomicAdd(&Qsum[hs4 * 4 + t], Q);
    }
}

// ---------------------------------------------------------------------------
// Kernel 3: normalize with inline scale/shift from the atomic accumulators.
// 256 blocks x 256 thr; Ssum/Qsum/gamma/beta reads are coalesced f4, L2-hot.
// ---------------------------------------------------------------------------
__global__ __launch_bounds__(256) void norm_kernel(
    const float* __restrict__ equ, const float* __restrict__ Ssum,
    const float* __restrict__ Qsum, const float* __restrict__ gamma,
    const float* __restrict__ beta, float* __restrict__ out)
{
    const int idx = blockIdx.x * 256 + threadIdx.x;   // f4 index
    const int c4  = idx & 63;
    f4 e = reinterpret_cast<const f4*>(equ)[idx];
    f4 S = reinterpret_cast<const f4*>(Ssum)[c4];
    f4 Q = reinterpret_cast<const f4*>(Qsum)[c4];
    f4 g = reinterpret_cast<const f4*>(gamma)[c4];
    f4 b = reinterpret_cast<const f4*>(beta)[c4];

    const float inv_n = 1.f / (float)(BB * NN);
    f4 o;
#pragma unroll
    for (int k = 0; k < 4; ++k) {
        float mean = S[k] * inv_n;
        float var  = Q[k] * inv_n - mean * mean;
        float rstd = rsqrtf(var + BN_EPS);
        o[k] = (e[k] - mean) * rstd * g[k] + b[k];
    }
    reinterpret_cast<f4*>(out)[idx] = o;
}

// ---------------------------------------------------------------------------
extern "C" void kernel_launch(void* const* d_in, const int* in_sizes, int n_in,
                              void* d_out, int out_size, void* d_ws, size_t ws_size,
                              hipStream_t stream) {
    (void)in_sizes; (void)n_in; (void)out_size; (void)ws_size;

    const float* nodes = (const float*)d_in[0];
    const float* edges = (const float*)d_in[1];
    const float* W1    = (const float*)d_in[2];
    const float* W2    = (const float*)d_in[3];
    const float* gamma = (const float*)d_in[4];
    const float* beta  = (const float*)d_in[5];
    float* out = (float*)d_out;

    const int nBN_H = BB * NN * HH;  // 262144
    float* ws    = (float*)d_ws;
    float* xleft = ws;
    float* xw2   = ws + nBN_H;
    float* equ   = ws + 2 * nBN_H;
    float* WT1   = ws + 3 * nBN_H;
    float* WT2   = WT1 + HH * HH;
    float* Ssum  = WT2 + HH * HH;
    float* Qsum  = Ssum + HH;

    transpose_kernel<<<33, 256, 0, stream>>>(W1, W2, WT1, WT2, Ssum, Qsum);
    proj_kernel<<<512, 256, 0, stream>>>(nodes, WT1, WT2, xleft, xw2);
    edge_kernel<<<512, 1024, 0, stream>>>(edges, xw2, xleft, equ, Ssum, Qsum);
    norm_kernel<<<256, 256, 0, stream>>>(equ, Ssum, Qsum, gamma, beta, out);
}